// Round 1
// baseline (373.492 us; speedup 1.0000x reference)
//
#include <hip/hip_runtime.h>
#include <cmath>

// Problem constants
#define BB 64
#define RR 4608
#define CC 32
#define INN 8
#define OUTT 16

constexpr int RC = 24;                 // r-rows per block
constexpr int NCHUNK = RR / RC;        // 192
constexpr int CT = 4;                  // c per block (one wave each)
constexpr int XS_STRIDE = RC * INN + 4; // 196 floats: 16B-aligned rows, bank-spread (196%32==4)

// One flash-style pass: for each (b,c,r) recompute uh[o] = sum_i x[b,r,i]*W[r,c,i,o],
// logit = uh . V[b,c,:]  (V==0 on iter 0 -> uniform softmax automatically),
// accumulate z += exp(logit), s[o] += exp(logit)*uh[o] over the block's r-chunk.
__global__ __launch_bounds__(256, 3)
void caps_pass(const float* __restrict__ x, const float* __restrict__ W,
               const float* __restrict__ V, float* __restrict__ pz,
               float* __restrict__ ps)
{
    __shared__ float xs[BB][XS_STRIDE];   // x chunk, transposed to [b][r*8+i]; 50 KB

    const int tid  = threadIdx.x;
    const int lane = tid & 63;            // = b
    const int wv   = tid >> 6;            // 0..3
    const int ch   = blockIdx.x;          // r-chunk id, 0..191
    const int r0   = ch * RC;
    const int c    = __builtin_amdgcn_readfirstlane(blockIdx.y * CT + wv);

    // ---- stage x[0:64][r0:r0+RC][0:8] into LDS (coalesced float4 reads) ----
    {
        const int F4_PER_B = (RC * INN) / 4;          // 48
        const int T4 = BB * F4_PER_B;                 // 3072
        for (int t4 = tid; t4 < T4; t4 += 256) {
            int b = t4 / F4_PER_B;
            int j = t4 % F4_PER_B;
            float4 v = *reinterpret_cast<const float4*>(
                x + ((size_t)b * RR + r0) * INN + 4 * j);
            *reinterpret_cast<float4*>(&xs[b][4 * j]) = v;
        }
    }
    __syncthreads();

    // ---- per-thread state: cumulative V for (b=lane, c) ----
    float Vr[OUTT];
    {
        const float* vp = V + ((size_t)c * BB + lane) * OUTT;
#pragma unroll
        for (int o = 0; o < OUTT; ++o) Vr[o] = vp[o];
    }

    float z = 0.f;
    float sacc[OUTT];
#pragma unroll
    for (int o = 0; o < OUTT; ++o) sacc[o] = 0.f;

    for (int r = 0; r < RC; ++r) {
        // x fragment for this (b, r): 8 floats, vector LDS reads
        float4 xA = *reinterpret_cast<const float4*>(&xs[lane][r * INN]);
        float4 xB = *reinterpret_cast<const float4*>(&xs[lane][r * INN + 4]);
        float xi[INN] = { xA.x, xA.y, xA.z, xA.w, xB.x, xB.y, xB.z, xB.w };

        const float* Wr = W + (((size_t)(r0 + r) * CC + c) * INN) * OUTT; // wave-uniform

        float uh[OUTT];
#pragma unroll
        for (int o = 0; o < OUTT; ++o) uh[o] = 0.f;
#pragma unroll
        for (int i = 0; i < INN; ++i) {
#pragma unroll
            for (int o = 0; o < OUTT; ++o)
                uh[o] = fmaf(xi[i], Wr[i * OUTT + o], uh[o]);
        }

        float logit = 0.f;
#pragma unroll
        for (int o = 0; o < OUTT; ++o) logit = fmaf(uh[o], Vr[o], logit);

        float p = __expf(logit);   // V=0 on iter0 => p=1 => uniform routing
        z += p;
#pragma unroll
        for (int o = 0; o < OUTT; ++o) sacc[o] = fmaf(p, uh[o], sacc[o]);
    }

    // ---- write partials ----
    const size_t base = ((size_t)ch * CC + c) * BB + lane;
    pz[base] = z;
    float* psp = ps + base * OUTT;
#pragma unroll
    for (int q = 0; q < OUTT / 4; ++q) {
        float4 v4 = make_float4(sacc[4 * q], sacc[4 * q + 1],
                                sacc[4 * q + 2], sacc[4 * q + 3]);
        *reinterpret_cast<float4*>(psp + 4 * q) = v4;
    }
}

// Combine partials over r-chunks, squash, and either accumulate V or emit output.
template <int LAST>
__global__ __launch_bounds__(256)
void caps_combine(const float* __restrict__ pz, const float* __restrict__ ps,
                  float* __restrict__ V, float* __restrict__ out)
{
    const int tid = blockIdx.x * 256 + threadIdx.x;  // 0..32767
    const int o  = tid & 15;
    const int bc = tid >> 4;        // 0..2047
    const int b  = bc & 63;
    const int c  = bc >> 6;

    float Z = 0.f, sv = 0.f;
    for (int ch = 0; ch < NCHUNK; ++ch) {
        const size_t base = ((size_t)ch * CC + c) * BB + b;
        Z  += pz[base];
        sv += ps[base * OUTT + o];
    }
    float st = sv / Z;              // s[b,c,o]

    // squash: reduce sum of squares across the 16 o-lanes (within 16-lane groups)
    float sq = st * st;
#pragma unroll
    for (int m = 1; m < 16; m <<= 1) sq += __shfl_xor(sq, m);
    float scale = (sq / (1.0f + sq)) / sqrtf(sq + 1e-8f);
    float v = st * scale;

    if (LAST) {
        out[((size_t)b * CC + c) * OUTT + o] = v;      // output layout (B,C,OUT)
    } else {
        V[((size_t)c * BB + b) * OUTT + o] += v;       // cumulative logit vector
    }
}

extern "C" void kernel_launch(void* const* d_in, const int* in_sizes, int n_in,
                              void* d_out, int out_size, void* d_ws, size_t ws_size,
                              hipStream_t stream)
{
    const float* x = (const float*)d_in[0];   // (B,R,IN)
    const float* W = (const float*)d_in[1];   // (R,C,IN,OUT)
    float* out = (float*)d_out;               // (B,C,OUT)

    float* wsf = (float*)d_ws;
    float* V  = wsf;                                    // 32768 floats
    float* pz = wsf + (size_t)BB * CC * OUTT;           // NCHUNK*C*B
    float* ps = pz + (size_t)NCHUNK * CC * BB;          // NCHUNK*C*B*16

    hipMemsetAsync(V, 0, (size_t)BB * CC * OUTT * sizeof(float), stream);

    dim3 grid(NCHUNK, CC / CT);
    for (int it = 0; it < 3; ++it) {
        caps_pass<<<grid, 256, 0, stream>>>(x, W, V, pz, ps);
        if (it < 2)
            caps_combine<0><<<128, 256, 0, stream>>>(pz, ps, V, out);
        else
            caps_combine<1><<<128, 256, 0, stream>>>(pz, ps, V, out);
    }
}